// Round 5
// baseline (67.708 us; speedup 1.0000x reference)
//
#include <hip/hip_runtime.h>
#include <hip/hip_bf16.h>
#include <math.h>

typedef short bf16x8 __attribute__((ext_vector_type(8)));
typedef float f32x4  __attribute__((ext_vector_type(4)));

static __device__ __forceinline__ unsigned short f2bf(float x) {
    unsigned u = __builtin_bit_cast(unsigned, x);
    return (unsigned short)((u + 0x7fffu + ((u >> 16) & 1u)) >> 16);
}

static __device__ __forceinline__ bf16x8 pack8(float4 u0, float4 u1) {
    bf16x8 f;
    f[0] = (short)f2bf(u0.x); f[1] = (short)f2bf(u0.y);
    f[2] = (short)f2bf(u0.z); f[3] = (short)f2bf(u0.w);
    f[4] = (short)f2bf(u1.x); f[5] = (short)f2bf(u1.y);
    f[6] = (short)f2bf(u1.z); f[7] = (short)f2bf(u1.w);
    return f;
}

static __device__ __forceinline__ void async_cp16(const void* gsrc, void* ldsdst) {
    __builtin_amdgcn_global_load_lds(
        (const __attribute__((address_space(1))) void*)gsrc,
        (__attribute__((address_space(3))) void*)ldsdst, 16, 0, 0);
}

// ---- centroid image + c2 + (block 64: label-width detect + zero out) --------
// img[cb16][k][lane][j] = cent[cb16*16 + (lane&15)][k*32 + (lane>>4)*8 + j]
__global__ __launch_bounds__(64) void cent_prep_kernel(
    const float* __restrict__ cent, char* __restrict__ Cimg,
    float* __restrict__ c2g, const unsigned* __restrict__ w, int nelem,
    unsigned* __restrict__ flag, float* __restrict__ out, int out_size, int ncb) {
    const int lane = threadIdx.x;
    if ((int)blockIdx.x < ncb) {
        const int cb = blockIdx.x;
        const int r = cb * 16 + (lane & 15);
        const int q = lane >> 4;
        const float4* C4 = (const float4*)cent;
        float s = 0.0f;
        #pragma unroll
        for (int k = 0; k < 8; ++k) {
            int fidx = r * 64 + k * 8 + q * 2;
            float4 u0 = C4[fidx], u1 = C4[fidx + 1];
            *(bf16x8*)(Cimg + ((size_t)(cb * 8 + k) * 64 + lane) * 16) = pack8(u0, u1);
            s += u0.x*u0.x + u0.y*u0.y + u0.z*u0.z + u0.w*u0.w
               + u1.x*u1.x + u1.y*u1.y + u1.z*u1.z + u1.w*u1.w;
        }
        s += __shfl_xor(s, 16, 64);
        s += __shfl_xor(s, 32, 64);
        if (lane < 16) c2g[cb * 16 + lane] = s;
    } else {
        // detect label width (sample first 4096 pairs) + zero the output
        int npairs = nelem / 2; if (npairs > 4096) npairs = 4096;
        unsigned acc = 0;
        for (int i = lane; i < npairs; i += 64) acc |= w[2 * i + 1];
        #pragma unroll
        for (int m = 32; m >= 1; m >>= 1) acc |= __shfl_xor(acc, m, 64);
        if (lane == 0) *flag = (acc != 0u) ? 1u : 0u;   // 1 = int32
        for (int i = lane; i < out_size; i += 64) out[i] = 0.0f;
    }
}

// ---- main: A fp32->reg-bf16 in-kernel, B double-buffered LDS, MFMA, epilogue -
#define CHUNK_BYTES 65536
// LDS: Bb0 @0, Bb1 @65536, c2l @131072 (4KB), e2l @135168 (512B),
//      lab @135680 (512B), red @136192 (64B)
#define MAIN_SMEM 136256

// NOTE: LDS (136 KB) already limits us to 1 block/CU, so do NOT constrain the
// register allocator: (512,1) gives the full 256-VGPR budget. (512,2) capped
// VGPRs at 128 and spilled the 128-VGPR A-fragment array to scratch
// (R4: WRITE_SIZE 46.5 MB on a kernel that writes one float per block).
__global__ __launch_bounds__(512, 1) void main2_kernel(
    const float* __restrict__ emb, const char* __restrict__ Cimg,
    const float* __restrict__ c2g, const int* __restrict__ labw,
    const unsigned* __restrict__ flag, float* __restrict__ out,
    int nchunk, float invB) {
    extern __shared__ char smem[];
    char*  Bb0 = smem;
    char*  Bb1 = smem + CHUNK_BYTES;
    float* c2l = (float*)(smem + 131072);
    float* e2l = (float*)(smem + 135168);
    int*   lab = (int*)(smem + 135680);
    float* red = (float*)(smem + 136192);

    const int tid = threadIdx.x, lane = tid & 63, wid = tid >> 6;
    const int wr = wid >> 2, wc = wid & 3;      // 2x4 wave grid, wave tile 64x32
    const int row0 = blockIdx.x * 128;
    const int l15 = lane & 15, q = lane >> 4;

    // stage chunk 0 of the centroid image (async, direct to LDS)
    #pragma unroll
    for (int i = 0; i < 8; ++i)
        async_cp16(Cimg + i * 8192 + tid * 16, Bb0 + i * 8192 + wid * 1024);

    // c2 -> LDS (1024 floats)
    c2l[tid] = c2g[tid];
    c2l[tid + 512] = c2g[tid + 512];
    // labels -> LDS (both widths)
    if (tid < 128) {
        int b = row0 + tid;
        lab[tid] = (*flag != 0u) ? labw[b] : labw[2 * b];
    }

    // A: load fp32 directly, convert to MFMA fragments in registers; e2 via shfl.
    // (waves with the same wr duplicate these reads; L2 absorbs the re-reads)
    bf16x8 a[4][8];
    #pragma unroll
    for (int m = 0; m < 4; ++m) {
        const int rg = row0 + wr * 64 + m * 16 + l15;
        const float4* E4 = (const float4*)emb + (size_t)rg * 64;
        float s = 0.0f;
        #pragma unroll
        for (int k = 0; k < 8; ++k) {
            float4 u0 = E4[k * 8 + q * 2], u1 = E4[k * 8 + q * 2 + 1];
            a[m][k] = pack8(u0, u1);
            s += u0.x*u0.x + u0.y*u0.y + u0.z*u0.z + u0.w*u0.w
               + u1.x*u1.x + u1.y*u1.y + u1.z*u1.z + u1.w*u1.w;
        }
        s += __shfl_xor(s, 16, 64);
        s += __shfl_xor(s, 32, 64);
        if (wc == 0 && lane < 16) e2l[wr * 64 + m * 16 + lane] = s;
    }

    float fsum = 0.0f;
    __syncthreads();   // drains async chunk0 + LDS writes

    for (int ch = 0; ch < nchunk; ++ch) {
        const char* Bcur = (ch & 1) ? Bb1 : Bb0;
        char* Bnxt = (ch & 1) ? Bb0 : Bb1;
        if (ch + 1 < nchunk) {
            const char* src = Cimg + (size_t)(ch + 1) * CHUNK_BYTES;
            #pragma unroll
            for (int i = 0; i < 8; ++i)
                async_cp16(src + i * 8192 + tid * 16, Bnxt + i * 8192 + wid * 1024);
        }

        f32x4 acc[4][2];
        #pragma unroll
        for (int m = 0; m < 4; ++m) {
            acc[m][0] = (f32x4){0.0f, 0.0f, 0.0f, 0.0f};
            acc[m][1] = (f32x4){0.0f, 0.0f, 0.0f, 0.0f};
        }
        const char* Bw = Bcur + wc * 16384 + lane * 16;
        #pragma unroll
        for (int k = 0; k < 8; ++k) {
            bf16x8 b0 = *(const bf16x8*)(Bw + k * 1024);
            bf16x8 b1 = *(const bf16x8*)(Bw + 8192 + k * 1024);
            #pragma unroll
            for (int m = 0; m < 4; ++m) {
                acc[m][0] = __builtin_amdgcn_mfma_f32_16x16x32_bf16(a[m][k], b0, acc[m][0], 0, 0, 0);
                acc[m][1] = __builtin_amdgcn_mfma_f32_16x16x32_bf16(a[m][k], b1, acc[m][1], 0, 0, 0);
            }
        }

        // ---- epilogue: pos term + margin screen per element ----
        float c2v[2]; int colg[2];
        #pragma unroll
        for (int n = 0; n < 2; ++n) {
            int cl = wc * 32 + n * 16 + l15;
            c2v[n] = c2l[ch * 128 + cl];
            colg[n] = ch * 128 + cl;
        }
        unsigned need = 0;
        #pragma unroll
        for (int m = 0; m < 4; ++m)
            #pragma unroll
            for (int r = 0; r < 4; ++r) {
                int rl = wr * 64 + m * 16 + q * 4 + r;
                float e2r = e2l[rl];
                int   lbr = lab[rl];
                #pragma unroll
                for (int n = 0; n < 2; ++n) {
                    float d2 = fmaf(-2.0f, acc[m][n][r], e2r + c2v[n]);
                    d2 = fmaxf(d2, 0.0f);
                    bool isp = (colg[n] == lbr);
                    fsum += isp ? d2 : 0.0f;
                    need |= (unsigned)((!isp) & (d2 < 1.0f)) << (m * 8 + r * 2 + n);
                }
            }
        if (__any(need != 0)) {   // rare: a non-label distance < MARGIN
            #pragma unroll
            for (int m = 0; m < 4; ++m)
                #pragma unroll
                for (int r = 0; r < 4; ++r) {
                    int rl = wr * 64 + m * 16 + q * 4 + r;
                    float e2r = e2l[rl];
                    #pragma unroll
                    for (int n = 0; n < 2; ++n)
                        if ((need >> (m * 8 + r * 2 + n)) & 1u) {
                            float d2 = fmaf(-2.0f, acc[m][n][r], e2r + c2v[n]);
                            d2 = fmaxf(d2, 0.0f);
                            float t = 1.0f - sqrtf(d2);
                            fsum += t * t;
                        }
                }
        }
        asm volatile("s_waitcnt vmcnt(0)" ::: "memory");
        __builtin_amdgcn_s_barrier();
    }

    #pragma unroll
    for (int m = 32; m >= 1; m >>= 1) fsum += __shfl_xor(fsum, m, 64);
    if (lane == 0) red[wid] = fsum;
    __syncthreads();
    if (tid == 0) {
        float t = 0.0f;
        #pragma unroll
        for (int w = 0; w < 8; ++w) t += red[w];
        atomicAdd(out, t * invB);
    }
}

// ======================= fallback (round-1, verified) ========================
#define FB_THREADS 512
#define FB_SMEM 132672
__device__ int g_lab_is64;

__global__ void fb_detect_kernel(const unsigned* __restrict__ w, int nelem,
                                 float* __restrict__ out, int out_size) {
    __shared__ unsigned red[256];
    unsigned acc = 0;
    for (int i = threadIdx.x; i < nelem / 2; i += 256) acc |= w[2 * i + 1];
    red[threadIdx.x] = acc;
    __syncthreads();
    for (int s = 128; s > 0; s >>= 1) {
        if (threadIdx.x < s) red[threadIdx.x] |= red[threadIdx.x + s];
        __syncthreads();
    }
    if (threadIdx.x == 0) g_lab_is64 = (red[0] == 0u) ? 1 : 0;
    for (int i = threadIdx.x; i < out_size; i += 256) out[i] = 0.0f;
}

__global__ __launch_bounds__(FB_THREADS) void fb_loss_kernel(
    const float* __restrict__ emb, const float* __restrict__ cent,
    const int* __restrict__ labw, float* __restrict__ out,
    int nchunk, float invB) {
    extern __shared__ char smem[];
    char* Abf = smem;
    char* Cbf = smem + 65536;
    float* e2 = (float*)(smem + 131072);
    float* c2 = (float*)(smem + 131584);
    int* lab = (int*)(smem + 132096);
    float* red = (float*)(smem + 132608);

    const int tid = threadIdx.x, lane = tid & 63, wid = tid >> 6;
    const int row0 = blockIdx.x * 128;
    const int is64 = g_lab_is64;

    for (int j = 0; j < 16; ++j) {
        int f4 = tid + j * FB_THREADS;
        int r = f4 >> 6, c4 = f4 & 63;
        float4 v = ((const float4*)emb)[(size_t)(row0 + r) * 64 + c4];
        ushort4 h;
        h.x = f2bf(v.x); h.y = f2bf(v.y); h.z = f2bf(v.z); h.w = f2bf(v.w);
        int off = (c4 * 8) ^ ((r & 7) << 4);
        *(ushort4*)(Abf + r * 512 + off) = h;
        float s = v.x*v.x + v.y*v.y + v.z*v.z + v.w*v.w;
        #pragma unroll
        for (int m = 32; m >= 1; m >>= 1) s += __shfl_xor(s, m, 64);
        if (lane == 0) e2[r] = s;
    }
    if (tid < 128) {
        int b = row0 + tid;
        lab[tid] = is64 ? labw[2 * b] : labw[b];
    }
    __syncthreads();

    const int wr = wid >> 1, wc = wid & 1;
    const int l15 = lane & 15, l16 = lane >> 4;
    const int swz = (l15 & 7) << 4;

    float e2v[2][4]; int labv[2][4];
    #pragma unroll
    for (int m = 0; m < 2; ++m)
        #pragma unroll
        for (int r = 0; r < 4; ++r) {
            int rr = wr * 32 + m * 16 + l16 * 4 + r;
            e2v[m][r] = e2[rr]; labv[m][r] = lab[rr];
        }

    float fsum = 0.0f;
    for (int ch = 0; ch < nchunk; ++ch) {
        const float* cbase = cent + (size_t)ch * 128 * 256;
        for (int j = 0; j < 16; ++j) {
            int f4 = tid + j * FB_THREADS;
            int r = f4 >> 6, c4 = f4 & 63;
            float4 v = ((const float4*)cbase)[(size_t)r * 64 + c4];
            ushort4 h;
            h.x = f2bf(v.x); h.y = f2bf(v.y); h.z = f2bf(v.z); h.w = f2bf(v.w);
            int off = (c4 * 8) ^ ((r & 7) << 4);
            *(ushort4*)(Cbf + r * 512 + off) = h;
            float s = v.x*v.x + v.y*v.y + v.z*v.z + v.w*v.w;
            #pragma unroll
            for (int m = 32; m >= 1; m >>= 1) s += __shfl_xor(s, m, 64);
            if (lane == 0) c2[r] = s;
        }
        __syncthreads();

        f32x4 acc[2][4];
        #pragma unroll
        for (int m = 0; m < 2; ++m)
            #pragma unroll
            for (int n = 0; n < 4; ++n) acc[m][n] = (f32x4){0, 0, 0, 0};

        #pragma unroll
        for (int kk = 0; kk < 8; ++kk) {
            int kb = kk * 64 + l16 * 16;
            bf16x8 a[2], b[4];
            #pragma unroll
            for (int m = 0; m < 2; ++m)
                a[m] = *(const bf16x8*)(Abf + (wr * 32 + m * 16 + l15) * 512 + (kb ^ swz));
            #pragma unroll
            for (int n = 0; n < 4; ++n)
                b[n] = *(const bf16x8*)(Cbf + (wc * 64 + n * 16 + l15) * 512 + (kb ^ swz));
            #pragma unroll
            for (int m = 0; m < 2; ++m)
                #pragma unroll
                for (int n = 0; n < 4; ++n)
                    acc[m][n] = __builtin_amdgcn_mfma_f32_16x16x32_bf16(a[m], b[n], acc[m][n], 0, 0, 0);
        }

        float c2v[4]; int colg[4];
        #pragma unroll
        for (int n = 0; n < 4; ++n) {
            int cl = wc * 64 + n * 16 + l15;
            c2v[n] = c2[cl]; colg[n] = ch * 128 + cl;
        }
        unsigned need = 0;
        #pragma unroll
        for (int m = 0; m < 2; ++m)
            #pragma unroll
            for (int n = 0; n < 4; ++n)
                #pragma unroll
                for (int r = 0; r < 4; ++r) {
                    float d2 = fmaf(-2.0f, acc[m][n][r], e2v[m][r] + c2v[n]);
                    d2 = fmaxf(d2, 0.0f);
                    bool isp = (colg[n] == labv[m][r]);
                    fsum += isp ? d2 : 0.0f;
                    need |= (unsigned)((!isp) & (d2 < 1.0f)) << (m * 16 + n * 4 + r);
                }
        if (__any(need != 0)) {
            #pragma unroll
            for (int m = 0; m < 2; ++m)
                #pragma unroll
                for (int n = 0; n < 4; ++n)
                    #pragma unroll
                    for (int r = 0; r < 4; ++r)
                        if ((need >> (m * 16 + n * 4 + r)) & 1u) {
                            float d2 = fmaf(-2.0f, acc[m][n][r], e2v[m][r] + c2v[n]);
                            d2 = fmaxf(d2, 0.0f);
                            float t = 1.0f - sqrtf(d2);
                            fsum += t * t;
                        }
        }
        __syncthreads();
    }
    #pragma unroll
    for (int m = 32; m >= 1; m >>= 1) fsum += __shfl_xor(fsum, m, 64);
    if (lane == 0) red[wid] = fsum;
    __syncthreads();
    if (tid == 0) {
        float t = 0.0f;
        #pragma unroll
        for (int w = 0; w < 8; ++w) t += red[w];
        atomicAdd(out, t * invB);
    }
}

// =============================================================================
extern "C" void kernel_launch(void* const* d_in, const int* in_sizes, int n_in,
                              void* d_out, int out_size, void* d_ws, size_t ws_size,
                              hipStream_t stream) {
    const float* emb = (const float*)d_in[0];
    const float* cent = (const float*)d_in[1];
    const int* labw = (const int*)d_in[2];
    float* out = (float*)d_out;

    const int B = in_sizes[0] / 256;
    const int K = in_sizes[1] / 256;
    const int nchunk = K / 128;
    const float invB = 1.0f / (float)B;

    char* ws = (char*)d_ws;
    const size_t off_flag = 0;
    const size_t off_c2 = 256;
    const size_t off_cimg = 8192;
    const size_t req = off_cimg + (size_t)K * 512;

    if (ws_size >= req) {
        const int ncb = K / 16;               // 64 centroid-image blocks
        cent_prep_kernel<<<ncb + 1, 64, 0, stream>>>(
            cent, ws + off_cimg, (float*)(ws + off_c2),
            (const unsigned*)d_in[2], in_sizes[2], (unsigned*)(ws + off_flag),
            out, out_size, ncb);

        hipFuncSetAttribute(reinterpret_cast<const void*>(main2_kernel),
                            hipFuncAttributeMaxDynamicSharedMemorySize, MAIN_SMEM);
        main2_kernel<<<B / 128, 512, MAIN_SMEM, stream>>>(
            emb, ws + off_cimg, (const float*)(ws + off_c2), labw,
            (const unsigned*)(ws + off_flag), out, nchunk, invB);
    } else {
        fb_detect_kernel<<<1, 256, 0, stream>>>((const unsigned*)d_in[2], in_sizes[2],
                                                out, out_size);
        hipFuncSetAttribute(reinterpret_cast<const void*>(fb_loss_kernel),
                            hipFuncAttributeMaxDynamicSharedMemorySize, FB_SMEM);
        fb_loss_kernel<<<B / 128, FB_THREADS, FB_SMEM, stream>>>(
            emb, cent, labw, out, nchunk, invB);
    }
}

// Round 6
// 48.090 us; speedup vs baseline: 1.4079x; 1.4079x over previous
//
#include <hip/hip_runtime.h>
#include <hip/hip_bf16.h>
#include <math.h>

typedef short bf16x8 __attribute__((ext_vector_type(8)));
typedef float f32x4  __attribute__((ext_vector_type(4)));

static __device__ __forceinline__ unsigned short f2bf(float x) {
    unsigned u = __builtin_bit_cast(unsigned, x);
    return (unsigned short)((u + 0x7fffu + ((u >> 16) & 1u)) >> 16);
}

static __device__ __forceinline__ bf16x8 pack8(float4 u0, float4 u1) {
    bf16x8 f;
    f[0] = (short)f2bf(u0.x); f[1] = (short)f2bf(u0.y);
    f[2] = (short)f2bf(u0.z); f[3] = (short)f2bf(u0.w);
    f[4] = (short)f2bf(u1.x); f[5] = (short)f2bf(u1.y);
    f[6] = (short)f2bf(u1.z); f[7] = (short)f2bf(u1.w);
    return f;
}

static __device__ __forceinline__ void async_cp16(const void* gsrc, void* ldsdst) {
    __builtin_amdgcn_global_load_lds(
        (const __attribute__((address_space(1))) void*)gsrc,
        (__attribute__((address_space(3))) void*)ldsdst, 16, 0, 0);
}

// ---- centroid image + c2 + (block ncb: label-width detect + zero out) -------
// img[cb16][k][lane][j] = cent[cb16*16 + (lane&15)][k*32 + (lane>>4)*8 + j]
__global__ __launch_bounds__(64) void cent_prep_kernel(
    const float* __restrict__ cent, char* __restrict__ Cimg,
    float* __restrict__ c2g, const unsigned* __restrict__ w, int nelem,
    unsigned* __restrict__ flag, float* __restrict__ out, int out_size, int ncb) {
    const int lane = threadIdx.x;
    if ((int)blockIdx.x < ncb) {
        const int cb = blockIdx.x;
        const int r = cb * 16 + (lane & 15);
        const int q = lane >> 4;
        const float4* C4 = (const float4*)cent;
        float s = 0.0f;
        #pragma unroll
        for (int k = 0; k < 8; ++k) {
            int fidx = r * 64 + k * 8 + q * 2;
            float4 u0 = C4[fidx], u1 = C4[fidx + 1];
            *(bf16x8*)(Cimg + ((size_t)(cb * 8 + k) * 64 + lane) * 16) = pack8(u0, u1);
            s += u0.x*u0.x + u0.y*u0.y + u0.z*u0.z + u0.w*u0.w
               + u1.x*u1.x + u1.y*u1.y + u1.z*u1.z + u1.w*u1.w;
        }
        s += __shfl_xor(s, 16, 64);
        s += __shfl_xor(s, 32, 64);
        if (lane < 16) c2g[cb * 16 + lane] = s;
    } else {
        // detect label width (sample first 4096 pairs) + zero the output
        int npairs = nelem / 2; if (npairs > 4096) npairs = 4096;
        unsigned acc = 0;
        for (int i = lane; i < npairs; i += 64) acc |= w[2 * i + 1];
        #pragma unroll
        for (int m = 32; m >= 1; m >>= 1) acc |= __shfl_xor(acc, m, 64);
        if (lane == 0) *flag = (acc != 0u) ? 1u : 0u;   // 1 = int32
        for (int i = lane; i < out_size; i += 64) out[i] = 0.0f;
    }
}

// ---- main: 8 waves = 8 row-groups of 16; each wave does all 128 cols --------
// A: a[8] in regs (32 VGPR, zero redundancy). B: double-buffered LDS image.
// Total live regs ~110 -> fits the 128-VGPR heuristic cap, no scratch spill
// (R5: a[4][8]=128 VGPRs spilled 46.5 MB to scratch; allocator ignores
// dynamic-LDS occupancy and caps at 128).
#define CHUNK_BYTES 65536
// LDS: Bb0 @0, Bb1 @65536, c2l @131072 (4KB), e2l @135168 (512B),
//      lab @135680 (512B), red @136192 (64B)
#define MAIN_SMEM 136256

__global__ __launch_bounds__(512) void main3_kernel(
    const float* __restrict__ emb, const char* __restrict__ Cimg,
    const float* __restrict__ c2g, const int* __restrict__ labw,
    const unsigned* __restrict__ flag, float* __restrict__ out,
    int nchunk, float invB) {
    extern __shared__ char smem[];
    char*  Bb0 = smem;
    char*  Bb1 = smem + CHUNK_BYTES;
    float* c2l = (float*)(smem + 131072);
    float* e2l = (float*)(smem + 135168);
    int*   lab = (int*)(smem + 135680);
    float* red = (float*)(smem + 136192);

    const int tid = threadIdx.x, lane = tid & 63, wid = tid >> 6;  // wid = row group
    const int row0 = blockIdx.x * 128;
    const int l15 = lane & 15, q = lane >> 4;

    // stage chunk 0 of the centroid image (async, direct to LDS)
    #pragma unroll
    for (int i = 0; i < 8; ++i)
        async_cp16(Cimg + i * 8192 + tid * 16, Bb0 + i * 8192 + wid * 1024);

    // c2 -> LDS (1024 floats)
    c2l[tid] = c2g[tid];
    c2l[tid + 512] = c2g[tid + 512];
    // labels -> LDS (both widths)
    if (tid < 128) {
        int b = row0 + tid;
        lab[tid] = (*flag != 0u) ? labw[b] : labw[2 * b];
    }

    // A: 16 rows per wave, fp32 -> bf16 fragments in registers; e2 via shfl.
    bf16x8 a[8];
    {
        const int rg = row0 + wid * 16 + l15;
        const float4* E4 = (const float4*)emb + (size_t)rg * 64;
        float s = 0.0f;
        #pragma unroll
        for (int k = 0; k < 8; ++k) {
            float4 u0 = E4[k * 8 + q * 2], u1 = E4[k * 8 + q * 2 + 1];
            a[k] = pack8(u0, u1);
            s += u0.x*u0.x + u0.y*u0.y + u0.z*u0.z + u0.w*u0.w
               + u1.x*u1.x + u1.y*u1.y + u1.z*u1.z + u1.w*u1.w;
        }
        s += __shfl_xor(s, 16, 64);
        s += __shfl_xor(s, 32, 64);
        if (lane < 16) e2l[wid * 16 + lane] = s;
    }

    float fsum = 0.0f;
    __syncthreads();   // drains async chunk0 + LDS writes

    // this wave's row metadata, hoisted once into registers
    float e2r[4]; int lbr[4];
    #pragma unroll
    for (int r = 0; r < 4; ++r) {
        int rl = wid * 16 + q * 4 + r;
        e2r[r] = e2l[rl];
        lbr[r] = lab[rl];
    }

    for (int ch = 0; ch < nchunk; ++ch) {
        const char* Bcur = (ch & 1) ? Bb1 : Bb0;
        char* Bnxt = (ch & 1) ? Bb0 : Bb1;
        if (ch + 1 < nchunk) {
            const char* src = Cimg + (size_t)(ch + 1) * CHUNK_BYTES;
            #pragma unroll
            for (int i = 0; i < 8; ++i)
                async_cp16(src + i * 8192 + tid * 16, Bnxt + i * 8192 + wid * 1024);
        }

        f32x4 acc[8];
        #pragma unroll
        for (int n = 0; n < 8; ++n) acc[n] = (f32x4){0.0f, 0.0f, 0.0f, 0.0f};

        #pragma unroll
        for (int k = 0; k < 8; ++k) {
            const char* Bk = Bcur + k * 1024 + lane * 16;
            #pragma unroll
            for (int n = 0; n < 8; ++n) {
                bf16x8 bn = *(const bf16x8*)(Bk + n * 8192);
                acc[n] = __builtin_amdgcn_mfma_f32_16x16x32_bf16(a[k], bn, acc[n], 0, 0, 0);
            }
        }

        // ---- epilogue: pos term + margin screen per element ----
        unsigned need = 0;
        #pragma unroll
        for (int n = 0; n < 8; ++n) {
            int cl = n * 16 + l15;
            float c2v = c2l[ch * 128 + cl];
            int colg = ch * 128 + cl;
            #pragma unroll
            for (int r = 0; r < 4; ++r) {
                float d2 = fmaf(-2.0f, acc[n][r], e2r[r] + c2v);
                d2 = fmaxf(d2, 0.0f);
                bool isp = (colg == lbr[r]);
                fsum += isp ? d2 : 0.0f;
                need |= (unsigned)((!isp) & (d2 < 1.0f)) << (n * 4 + r);
            }
        }
        if (__any(need != 0)) {   // rare: a non-label distance < MARGIN
            #pragma unroll
            for (int n = 0; n < 8; ++n) {
                int cl = n * 16 + l15;
                float c2v = c2l[ch * 128 + cl];
                #pragma unroll
                for (int r = 0; r < 4; ++r)
                    if ((need >> (n * 4 + r)) & 1u) {
                        float d2 = fmaf(-2.0f, acc[n][r], e2r[r] + c2v);
                        d2 = fmaxf(d2, 0.0f);
                        float t = 1.0f - sqrtf(d2);
                        fsum += t * t;
                    }
            }
        }
        asm volatile("s_waitcnt vmcnt(0)" ::: "memory");
        __builtin_amdgcn_s_barrier();
    }

    #pragma unroll
    for (int m = 32; m >= 1; m >>= 1) fsum += __shfl_xor(fsum, m, 64);
    if (lane == 0) red[wid] = fsum;
    __syncthreads();
    if (tid == 0) {
        float t = 0.0f;
        #pragma unroll
        for (int w = 0; w < 8; ++w) t += red[w];
        atomicAdd(out, t * invB);
    }
}

// ======================= fallback (round-1, verified) ========================
#define FB_THREADS 512
#define FB_SMEM 132672
__device__ int g_lab_is64;

__global__ void fb_detect_kernel(const unsigned* __restrict__ w, int nelem,
                                 float* __restrict__ out, int out_size) {
    __shared__ unsigned red[256];
    unsigned acc = 0;
    for (int i = threadIdx.x; i < nelem / 2; i += 256) acc |= w[2 * i + 1];
    red[threadIdx.x] = acc;
    __syncthreads();
    for (int s = 128; s > 0; s >>= 1) {
        if (threadIdx.x < s) red[threadIdx.x] |= red[threadIdx.x + s];
        __syncthreads();
    }
    if (threadIdx.x == 0) g_lab_is64 = (red[0] == 0u) ? 1 : 0;
    for (int i = threadIdx.x; i < out_size; i += 256) out[i] = 0.0f;
}

__global__ __launch_bounds__(FB_THREADS) void fb_loss_kernel(
    const float* __restrict__ emb, const float* __restrict__ cent,
    const int* __restrict__ labw, float* __restrict__ out,
    int nchunk, float invB) {
    extern __shared__ char smem[];
    char* Abf = smem;
    char* Cbf = smem + 65536;
    float* e2 = (float*)(smem + 131072);
    float* c2 = (float*)(smem + 131584);
    int* lab = (int*)(smem + 132096);
    float* red = (float*)(smem + 132608);

    const int tid = threadIdx.x, lane = tid & 63, wid = tid >> 6;
    const int row0 = blockIdx.x * 128;
    const int is64 = g_lab_is64;

    for (int j = 0; j < 16; ++j) {
        int f4 = tid + j * FB_THREADS;
        int r = f4 >> 6, c4 = f4 & 63;
        float4 v = ((const float4*)emb)[(size_t)(row0 + r) * 64 + c4];
        ushort4 h;
        h.x = f2bf(v.x); h.y = f2bf(v.y); h.z = f2bf(v.z); h.w = f2bf(v.w);
        int off = (c4 * 8) ^ ((r & 7) << 4);
        *(ushort4*)(Abf + r * 512 + off) = h;
        float s = v.x*v.x + v.y*v.y + v.z*v.z + v.w*v.w;
        #pragma unroll
        for (int m = 32; m >= 1; m >>= 1) s += __shfl_xor(s, m, 64);
        if (lane == 0) e2[r] = s;
    }
    if (tid < 128) {
        int b = row0 + tid;
        lab[tid] = is64 ? labw[2 * b] : labw[b];
    }
    __syncthreads();

    const int wr = wid >> 1, wc = wid & 1;
    const int l15 = lane & 15, l16 = lane >> 4;
    const int swz = (l15 & 7) << 4;

    float e2v[2][4]; int labv[2][4];
    #pragma unroll
    for (int m = 0; m < 2; ++m)
        #pragma unroll
        for (int r = 0; r < 4; ++r) {
            int rr = wr * 32 + m * 16 + l16 * 4 + r;
            e2v[m][r] = e2[rr]; labv[m][r] = lab[rr];
        }

    float fsum = 0.0f;
    for (int ch = 0; ch < nchunk; ++ch) {
        const float* cbase = cent + (size_t)ch * 128 * 256;
        for (int j = 0; j < 16; ++j) {
            int f4 = tid + j * FB_THREADS;
            int r = f4 >> 6, c4 = f4 & 63;
            float4 v = ((const float4*)cbase)[(size_t)r * 64 + c4];
            ushort4 h;
            h.x = f2bf(v.x); h.y = f2bf(v.y); h.z = f2bf(v.z); h.w = f2bf(v.w);
            int off = (c4 * 8) ^ ((r & 7) << 4);
            *(ushort4*)(Cbf + r * 512 + off) = h;
            float s = v.x*v.x + v.y*v.y + v.z*v.z + v.w*v.w;
            #pragma unroll
            for (int m = 32; m >= 1; m >>= 1) s += __shfl_xor(s, m, 64);
            if (lane == 0) c2[r] = s;
        }
        __syncthreads();

        f32x4 acc[2][4];
        #pragma unroll
        for (int m = 0; m < 2; ++m)
            #pragma unroll
            for (int n = 0; n < 4; ++n) acc[m][n] = (f32x4){0, 0, 0, 0};

        #pragma unroll
        for (int kk = 0; kk < 8; ++kk) {
            int kb = kk * 64 + l16 * 16;
            bf16x8 a[2], b[4];
            #pragma unroll
            for (int m = 0; m < 2; ++m)
                a[m] = *(const bf16x8*)(Abf + (wr * 32 + m * 16 + l15) * 512 + (kb ^ swz));
            #pragma unroll
            for (int n = 0; n < 4; ++n)
                b[n] = *(const bf16x8*)(Cbf + (wc * 64 + n * 16 + l15) * 512 + (kb ^ swz));
            #pragma unroll
            for (int m = 0; m < 2; ++m)
                #pragma unroll
                for (int n = 0; n < 4; ++n)
                    acc[m][n] = __builtin_amdgcn_mfma_f32_16x16x32_bf16(a[m], b[n], acc[m][n], 0, 0, 0);
        }

        float c2v[4]; int colg[4];
        #pragma unroll
        for (int n = 0; n < 4; ++n) {
            int cl = wc * 64 + n * 16 + l15;
            c2v[n] = c2[cl]; colg[n] = ch * 128 + cl;
        }
        unsigned need = 0;
        #pragma unroll
        for (int m = 0; m < 2; ++m)
            #pragma unroll
            for (int n = 0; n < 4; ++n)
                #pragma unroll
                for (int r = 0; r < 4; ++r) {
                    float d2 = fmaf(-2.0f, acc[m][n][r], e2v[m][r] + c2v[n]);
                    d2 = fmaxf(d2, 0.0f);
                    bool isp = (colg[n] == labv[m][r]);
                    fsum += isp ? d2 : 0.0f;
                    need |= (unsigned)((!isp) & (d2 < 1.0f)) << (m * 16 + n * 4 + r);
                }
        if (__any(need != 0)) {
            #pragma unroll
            for (int m = 0; m < 2; ++m)
                #pragma unroll
                for (int n = 0; n < 4; ++n)
                    #pragma unroll
                    for (int r = 0; r < 4; ++r)
                        if ((need >> (m * 16 + n * 4 + r)) & 1u) {
                            float d2 = fmaf(-2.0f, acc[m][n][r], e2v[m][r] + c2v[n]);
                            d2 = fmaxf(d2, 0.0f);
                            float t = 1.0f - sqrtf(d2);
                            fsum += t * t;
                        }
        }
        __syncthreads();
    }
    #pragma unroll
    for (int m = 32; m >= 1; m >>= 1) fsum += __shfl_xor(fsum, m, 64);
    if (lane == 0) red[wid] = fsum;
    __syncthreads();
    if (tid == 0) {
        float t = 0.0f;
        #pragma unroll
        for (int w = 0; w < 8; ++w) t += red[w];
        atomicAdd(out, t * invB);
    }
}

// =============================================================================
extern "C" void kernel_launch(void* const* d_in, const int* in_sizes, int n_in,
                              void* d_out, int out_size, void* d_ws, size_t ws_size,
                              hipStream_t stream) {
    const float* emb = (const float*)d_in[0];
    const float* cent = (const float*)d_in[1];
    const int* labw = (const int*)d_in[2];
    float* out = (float*)d_out;

    const int B = in_sizes[0] / 256;
    const int K = in_sizes[1] / 256;
    const int nchunk = K / 128;
    const float invB = 1.0f / (float)B;

    char* ws = (char*)d_ws;
    const size_t off_flag = 0;
    const size_t off_c2 = 256;
    const size_t off_cimg = 8192;
    const size_t req = off_cimg + (size_t)K * 512;

    if (ws_size >= req) {
        const int ncb = K / 16;               // 64 centroid-image blocks
        cent_prep_kernel<<<ncb + 1, 64, 0, stream>>>(
            cent, ws + off_cimg, (float*)(ws + off_c2),
            (const unsigned*)d_in[2], in_sizes[2], (unsigned*)(ws + off_flag),
            out, out_size, ncb);

        hipFuncSetAttribute(reinterpret_cast<const void*>(main3_kernel),
                            hipFuncAttributeMaxDynamicSharedMemorySize, MAIN_SMEM);
        main3_kernel<<<B / 128, 512, MAIN_SMEM, stream>>>(
            emb, ws + off_cimg, (const float*)(ws + off_c2), labw,
            (const unsigned*)(ws + off_flag), out, nchunk, invB);
    } else {
        fb_detect_kernel<<<1, 256, 0, stream>>>((const unsigned*)d_in[2], in_sizes[2],
                                                out, out_size);
        hipFuncSetAttribute(reinterpret_cast<const void*>(fb_loss_kernel),
                            hipFuncAttributeMaxDynamicSharedMemorySize, FB_SMEM);
        fb_loss_kernel<<<B / 128, FB_THREADS, FB_SMEM, stream>>>(
            emb, cent, labw, out, nchunk, invB);
    }
}